// Round 6
// baseline (241.795 us; speedup 1.0000x reference)
//
#include <hip/hip_runtime.h>
#include <stdint.h>

#define NEG_SLOPE 0.01f
#define HPG 32        // heads per block in k4_fused
#define TSTR 72       // padded T row stride (halfwords)
#define BSH 8         // head-bucket shift: bucket = head >> 8 (256 heads)
#define NBMAX 512     // max buckets (N=100K -> 391)
#define K1CH 8192     // edges per k1_bin block
#define NBLKMAX 1024  // max k1 blocks (E up to 8.4M)

typedef float f32x4 __attribute__((ext_vector_type(4)));
typedef float f32x2 __attribute__((ext_vector_type(2)));
typedef short short8 __attribute__((ext_vector_type(8)));
typedef unsigned int u32;

// DPP butterfly adds (VALU): 0xB1 quad_perm xor1, 0x4E quad_perm xor2,
// 0x141 row_half_mirror (combines the two quads of an 8-group),
// 0x128 row_ror:8 (xor-8 within the 16-lane row).
#define DPPADD(v, ctrl) ((v) + __int_as_float(__builtin_amdgcn_update_dpp( \
        0, __float_as_int(v), (ctrl), 0xF, 0xF, true)))

__device__ inline short f2bf(float f) {
    union { float f; uint32_t u; } x; x.f = f;
    uint32_t r = x.u + 0x7FFF + ((x.u >> 16) & 1);   // RNE
    return (short)(r >> 16);
}

// ---- K_init: zero head counters + ego fp32->bf16 + W^T frag pack ----------
__global__ void __launch_bounds__(256) k_init_bf(
        const float* __restrict__ ego, unsigned short* __restrict__ ego_bf,
        int NE8, int* head_cnt, int N,
        const float* __restrict__ rw, short* __restrict__ wfrag) {
    int i = blockIdx.x * 256 + threadIdx.x;
    if (i < N) head_cnt[i] = 0;
    if (blockIdx.x < 16) {                 // W^T frag pack: blocks 0..15
        int r = blockIdx.x;
        int tid = threadIdx.x;
        int lane = tid & 63;
        int c = lane & 15, q = lane >> 4;
        for (int ph = 0; ph < 2; ++ph) {
            int pair = (tid >> 6) + ph * 4;
            int t4 = pair >> 1, kh = pair & 1;
            int m = t4 * 16 + c;
            short8 f;
            for (int j = 0; j < 8; ++j) {
                int k = kh * 32 + q * 8 + j;
                f[j] = f2bf(rw[r * 4096 + k * 64 + m]);
            }
            *(short8*)(wfrag + ((size_t)((r * 4 + t4) * 2 + kh) * 64 + lane) * 8) = f;
        }
    }
    if (i >= NE8) return;
    const float4* p = (const float4*)ego + (size_t)i * 2;
    float4 a = p[0], b = p[1];
    short8 v;
    v[0] = f2bf(a.x); v[1] = f2bf(a.y); v[2] = f2bf(a.z); v[3] = f2bf(a.w);
    v[4] = f2bf(b.x); v[5] = f2bf(b.y); v[6] = f2bf(b.z); v[7] = f2bf(b.w);
    *(short8*)(ego_bf + (size_t)i * 8) = v;
}

// ---- K1: two-pass count + bucket-bin; 4B packed staging records -----------
// rec = tail(0..19) | type<<20 | (h & 255)<<24; bucket known from segment.
__global__ void __launch_bounds__(512) k1_bin(
        const int* __restrict__ head, const int* __restrict__ tail,
        const int* __restrict__ etype, int E, int NB,
        int* head_cnt, u32* __restrict__ staging, int* __restrict__ blk_off) {
    __shared__ int lcnt[NBMAX], lfill[NBMAX];
    int t = threadIdx.x;
    for (int b = t; b < NBMAX; b += 512) lcnt[b] = 0;
    __syncthreads();
    long long base = (long long)blockIdx.x * K1CH;
    #pragma unroll
    for (int s = 0; s < K1CH / 512; ++s) {           // pass 1: count only
        long long e = base + t + s * 512;
        if (e < E) {
            int h = head[e];
            atomicAdd(&lcnt[h >> BSH], 1);
            atomicAdd(&head_cnt[h], 1);              // no-return atomic
        }
    }
    __syncthreads();
    if (t < 64) {                          // exclusive scan, 8 buckets/lane
        int cl[8]; int cs = 0;
        #pragma unroll
        for (int j = 0; j < 8; ++j) { cl[j] = lcnt[t * 8 + j]; cs += cl[j]; }
        int inc = cs;
        for (int off = 1; off < 64; off <<= 1) {
            int u = __shfl_up(inc, off);
            if (t >= off) inc += u;
        }
        int run = inc - cs;
        #pragma unroll
        for (int j = 0; j < 8; ++j) { lfill[t * 8 + j] = run; run += cl[j]; }
    }
    __syncthreads();
    int* bo = blk_off + (size_t)blockIdx.x * (NBMAX + 1);
    for (int b = t; b < NB; b += 512) bo[b] = lfill[b];
    if (t == 0) {
        long long nv = (long long)E - base;
        bo[NB] = (int)(nv < K1CH ? nv : K1CH);
    }
    __syncthreads();                                  // bo reads done before mutate
    #pragma unroll
    for (int s = 0; s < K1CH / 512; ++s) {           // pass 2: place
        long long e = base + t + s * 512;
        if (e < E) {
            int h = head[e];
            int rk = atomicAdd(&lfill[h >> BSH], 1);
            staging[base + rk] = (u32)tail[e] | ((u32)etype[e] << 20)
                               | ((u32)(h & ((1 << BSH) - 1)) << 24);
        }
    }
}

// ---- K2a: per-block partial sums of head_cnt -------------------------------
__global__ void __launch_bounds__(512) k2a(const int* __restrict__ head_cnt,
                                           int N, int* partial) {
    __shared__ int sw[8];
    int i = blockIdx.x * 512 + threadIdx.x;
    int v = (i < N) ? head_cnt[i] : 0;
    for (int off = 32; off; off >>= 1) v += __shfl_down(v, off);
    int w = threadIdx.x >> 6, lane = threadIdx.x & 63;
    if (lane == 0) sw[w] = v;
    __syncthreads();
    if (threadIdx.x == 0) {
        int s = 0;
        for (int j = 0; j < 8; ++j) s += sw[j];
        partial[blockIdx.x] = s;
    }
}

// ---- K2c: scan -> head_off -------------------------------------------------
__global__ void __launch_bounds__(512) k2c(const int* __restrict__ head_cnt,
                                           int N, const int* __restrict__ partial,
                                           int* head_off, int E) {
    __shared__ int s[512];
    __shared__ int bo_s;
    int t = threadIdx.x;
    if (t < 64) {
        int acc = 0;
        for (int i = t; i < blockIdx.x; i += 64) acc += partial[i];
        for (int off = 32; off; off >>= 1) acc += __shfl_down(acc, off);
        if (t == 0) bo_s = acc;
    }
    int i = blockIdx.x * 512 + t;
    int v = (i < N) ? head_cnt[i] : 0;
    s[t] = v;
    __syncthreads();
    for (int off = 1; off < 512; off <<= 1) {
        int x = (t >= off) ? s[t - off] : 0;
        __syncthreads();
        s[t] += x;
        __syncthreads();
    }
    if (i < N) head_off[i] = s[t] - v + bo_s;
    if (i == 0) head_off[N] = E;
}

// ---- K3b: flat-walk per bucket: dense 512-thread placement -----------------
// Block b scans its bucket's segment lengths across all k1-blocks, prefix-
// sums in LDS, then every thread owns flat indices t, t+512, ... -> full lane
// utilization and ~coalesced staging reads. Dest window ~13KB, L2-local.
__global__ void __launch_bounds__(512) k3b_rank(
        const u32* __restrict__ staging, const int* __restrict__ blk_off,
        int nblk, const int* __restrict__ head_off, int* __restrict__ recs2) {
    __shared__ int soff[NBLKMAX], spre[NBLKMAX + 1];
    __shared__ int lcnt[1 << BSH];
    int t = threadIdx.x;
    if (t < (1 << BSH)) lcnt[t] = 0;
    int b = blockIdx.x;
    for (int i = t; i < nblk; i += 512) {
        const int* bo = blk_off + (size_t)i * (NBMAX + 1) + b;
        int o0 = bo[0];
        soff[i] = o0;
        spre[i] = bo[1] - o0;                         // length; scanned below
    }
    __syncthreads();
    if (t < 64) {                                     // chunked exclusive scan
        int carry = 0;
        for (int c0 = 0; c0 < nblk; c0 += 64) {
            int idx = c0 + t;
            int v = (idx < nblk) ? spre[idx] : 0;
            int inc = v;
            for (int off = 1; off < 64; off <<= 1) {
                int u = __shfl_up(inc, off);
                if (t >= off) inc += u;
            }
            if (idx < nblk) spre[idx] = inc - v + carry;
            carry += __shfl(inc, 63);
        }
        if (t == 0) spre[nblk] = carry;
    }
    __syncthreads();
    int total = spre[nblk];
    int hbase = b << BSH;
    for (int t0 = t; t0 < total; t0 += 512) {
        int lo = 0, hi = nblk;                        // find seg: spre[lo]<=t0
        while (hi - lo > 1) {
            int mid = (lo + hi) >> 1;
            if (spre[mid] <= t0) lo = mid; else hi = mid;
        }
        u32 rec = staging[(size_t)lo * K1CH + soff[lo] + (t0 - spre[lo])];
        int uh = rec >> 24;
        int rk = atomicAdd(&lcnt[uh], 1);
        recs2[head_off[hbase + uh] + rk] = (int)(rec & 0xFFFFFF);
    }
}

// ---- K4: fused transform + score + softmax + aggregate ---------------------
// Phase 2: 2-deep pipeline (load recs b+2 / gather rows b+1 / compute b);
// compute uses packed f32 (v_pk_fma) with a separate unguarded full-batch path.
__global__ void __launch_bounds__(512, 4) k4_fused(
        const unsigned short* __restrict__ ego_bf,
        const short* __restrict__ wfrag,
        const int* __restrict__ recs2,
        const int* __restrict__ head_off,
        float* __restrict__ out, int N) {
    __shared__ unsigned short T[16 * HPG * TSTR];   // 73,728 B -> 2 blocks/CU
    int tid = threadIdx.x;
    int wave = tid >> 6;
    int lane = tid & 63;
    int c = lane & 15, q = lane >> 4;
    int hb = blockIdx.x * HPG;

    // ---------------- phase 1: per-wave 2 types x 32 heads ----------------
    for (int t = 0; t < 2; ++t) {
        int r = wave * 2 + t;
        const short* wp = wfrag + (size_t)r * 4096;
        short8 wf[4][2];
        #pragma unroll
        for (int t4 = 0; t4 < 4; ++t4)
            #pragma unroll
            for (int kh = 0; kh < 2; ++kh)
                wf[t4][kh] = *(const short8*)(wp + ((size_t)((t4 * 2 + kh) * 64 + lane)) * 8);
        #pragma unroll
        for (int hf = 0; hf < 2; ++hf) {
            int hrow = hb + hf * 16 + c;
            if (hrow >= N) hrow = N - 1;           // clamp; garbage T never read
            const unsigned short* hr = ego_bf + (size_t)hrow * 64;
            short8 b0 = *(const short8*)(hr + q * 8);
            short8 b1 = *(const short8*)(hr + 32 + q * 8);
            #pragma unroll
            for (int t4 = 0; t4 < 4; ++t4) {
                f32x4 a = {0.f, 0.f, 0.f, 0.f};
                a = __builtin_amdgcn_mfma_f32_16x16x32_bf16(wf[t4][0], b0, a, 0, 0, 0);
                a = __builtin_amdgcn_mfma_f32_16x16x32_bf16(wf[t4][1], b1, a, 0, 0, 0);
                ushort4 us;
                us.x = (unsigned short)f2bf(a[0]);
                us.y = (unsigned short)f2bf(a[1]);
                us.z = (unsigned short)f2bf(a[2]);
                us.w = (unsigned short)f2bf(a[3]);
                *(ushort4*)&T[(size_t)(r * HPG + hf * 16 + c) * TSTR + t4 * 16 + q * 4] = us;
            }
        }
    }
    __syncthreads();

    // ---------------- phase 2: quarter (wave,q) owns head hb + wave*4 + q --
    int hql = wave * 4 + q;
    int h = hb + hql;
    if (h >= N) return;
    int lq = c;                   // lane within quarter
    int g2 = lq >> 3, c8 = lq & 7;
    int qb = q * 16;
    int s0 = head_off[h], s1 = head_off[h + 1];
    int cnt = s1 - s0;
    int nbt = (cnt + 15) >> 4;
    f32x2 acc2[4] = {{0.f,0.f},{0.f,0.f},{0.f,0.f},{0.f,0.f}};
    float den = 0.f;

    auto loadRec = [&](int b) -> int {             // one coalesced 4B/lane load
        if (b >= nbt) return 0;
        int idx = s0 + b * 16 + lq;
        return (idx < s1) ? recs2[idx] : 0;
    };
    auto body = [&](int sIt, const int* rj, const short8* rows, int ng, bool full) {
        short8 trwv = *(const short8*)&T[(size_t)(((u32)rj[sIt] >> 20) * HPG + hql) * TSTR + c8 * 8];
        const u32* ru = (const u32*)&rows[sIt];
        const u32* tu = (const u32*)&trwv;
        f32x2 sac = {0.f, 0.f};
        f32x2 rf[4];
        #pragma unroll
        for (int p = 0; p < 4; ++p) {
            u32 ua = ru[p], ub = tu[p];
            f32x2 r2 = { __uint_as_float(ua << 16), __uint_as_float(ua & 0xFFFF0000u) };
            f32x2 t2 = { __uint_as_float(ub << 16), __uint_as_float(ub & 0xFFFF0000u) };
            rf[p] = r2;
            sac = __builtin_elementwise_fma(r2, t2, sac);   // v_pk_fma_f32
        }
        float s = sac.x + sac.y;
        s = DPPADD(s, 0xB1);               // xor1
        s = DPPADD(s, 0x4E);               // xor2
        s = DPPADD(s, 0x141);              // other quad
        float lr = s > 0.f ? s : NEG_SLOPE * s;
        float w = __expf(lr);
        if (!full && (sIt * 2 + g2 >= ng)) w = 0.f;   // kill pad edge
        den += w;
        f32x2 w2 = {w, w};
        #pragma unroll
        for (int p = 0; p < 4; ++p)
            acc2[p] = __builtin_elementwise_fma(w2, rf[p], acc2[p]);
    };

    int rjA[8]; short8 rowsA[8];
    int recL1;
    {
        int recL0 = loadRec(0);
        #pragma unroll
        for (int j = 0; j < 8; ++j) rjA[j] = __shfl(recL0, qb + j * 2 + g2);
        #pragma unroll
        for (int j = 0; j < 8; ++j)
            rowsA[j] = *(const short8*)(ego_bf + (size_t)(rjA[j] & 0xFFFFF) * 64 + c8 * 8);
        recL1 = loadRec(1);
    }
    for (int b = 0; b < nbt; ++b) {
        int recL2 = loadRec(b + 2);                // S(b+2)
        int rjB[8]; short8 rowsB[8];
        #pragma unroll
        for (int j = 0; j < 8; ++j) rjB[j] = __shfl(recL1, qb + j * 2 + g2);
        #pragma unroll
        for (int j = 0; j < 8; ++j)                // G(b+1): in flight across C(b)
            rowsB[j] = *(const short8*)(ego_bf + (size_t)(rjB[j] & 0xFFFFF) * 64 + c8 * 8);
        int ng = s1 - (s0 + b * 16); if (ng > 16) ng = 16;
        if (ng == 16) {
            #pragma unroll
            for (int sIt = 0; sIt < 8; ++sIt) body(sIt, rjA, rowsA, 16, true);
        } else {
            #pragma unroll
            for (int sIt = 0; sIt < 8; ++sIt)
                if (sIt * 2 < ng) body(sIt, rjA, rowsA, ng, false);
        }
        recL1 = recL2;
        #pragma unroll
        for (int j = 0; j < 8; ++j) { rjA[j] = rjB[j]; rowsA[j] = rowsB[j]; }
    }
    den = DPPADD(den, 0x128);                      // combine 2 edge slots
    float accs[8] = {acc2[0].x, acc2[0].y, acc2[1].x, acc2[1].y,
                     acc2[2].x, acc2[2].y, acc2[3].x, acc2[3].y};
    #pragma unroll
    for (int k = 0; k < 8; ++k) accs[k] = DPPADD(accs[k], 0x128);
    if (g2 == 0) {
        float sc = (cnt > 0) ? 1.f / (den * (float)cnt) : 0.f;
        float4 v0 = {accs[0] * sc, accs[1] * sc, accs[2] * sc, accs[3] * sc};
        float4 v1 = {accs[4] * sc, accs[5] * sc, accs[6] * sc, accs[7] * sc};
        float* op = out + (size_t)h * 64 + c8 * 8;
        *(float4*)op = v0;
        *(float4*)(op + 4) = v1;
    }
}

extern "C" void kernel_launch(void* const* d_in, const int* in_sizes, int n_in,
                              void* d_out, int out_size, void* d_ws, size_t ws_size,
                              hipStream_t stream) {
    const float* ego = (const float*)d_in[0];
    const float* rw  = (const float*)d_in[1];
    const int* eidx  = (const int*)d_in[2];
    const int* etyp  = (const int*)d_in[3];
    int N = in_sizes[0] / 64;
    int E = in_sizes[3];
    const int* head = eidx;
    const int* tail = eidx + E;
    float* out = (float*)d_out;

    char* ws = (char*)d_ws;
    size_t o = 0;
    auto take = [&](size_t bytes) -> char* {
        char* p = ws + o;
        o = (o + bytes + 255) & ~(size_t)255;
        return p;
    };
    int nb2 = (N + 511) / 512;
    int NB = (N + (1 << BSH) - 1) >> BSH;
    if (NB > NBMAX) NB = NBMAX;            // defensive; N=100K -> 391
    int nblk = (E + K1CH - 1) / K1CH;      // 5M -> 611 (< NBLKMAX)
    unsigned short* ego_bf = (unsigned short*)take((size_t)N * 64 * 2);
    short* wfrag    = (short*)take(16 * 4096 * 2);
    int* recs2      = (int*)take((size_t)E * 4);
    u32* staging    = (u32*)take((size_t)nblk * K1CH * 4);
    int* blk_off    = (int*)take((size_t)nblk * (NBMAX + 1) * 4);
    int* head_cnt   = (int*)take((size_t)N * 4);
    int* head_off   = (int*)take((size_t)(N + 1) * 4);
    int* partial    = (int*)take((size_t)nb2 * 4);
    (void)ws_size; (void)n_in; (void)out_size;

    int NE8 = N * 8;
    k_init_bf<<<(NE8 + 255) / 256, 256, 0, stream>>>(ego, ego_bf, NE8,
                                                     head_cnt, N, rw, wfrag);
    k1_bin<<<nblk, 512, 0, stream>>>(head, tail, etyp, E, NB,
                                     head_cnt, staging, blk_off);
    k2a<<<nb2, 512, 0, stream>>>(head_cnt, N, partial);
    k2c<<<nb2, 512, 0, stream>>>(head_cnt, N, partial, head_off, E);
    k3b_rank<<<NB, 512, 0, stream>>>(staging, blk_off, nblk, head_off, recs2);
    k4_fused<<<(N + HPG - 1) / HPG, 512, 0, stream>>>(ego_bf, wfrag, recs2,
                                                      head_off, out, N);
}

// Round 7
// 199.305 us; speedup vs baseline: 1.2132x; 1.2132x over previous
//
#include <hip/hip_runtime.h>
#include <stdint.h>

#define NEG_SLOPE 0.01f
#define HPG 32        // heads per block in k4_fused
#define TSTR 72       // padded T row stride (halfwords)
#define BSH 8         // head-bucket shift: bucket = head >> 8 (256 heads)
#define NBMAX 512     // max buckets (N=100K -> 391)
#define K1CH 8192     // edges per k1_bin block
#define NBLKMAX 1024  // max k1 blocks (E up to 8.4M)
#define CAP 16384     // k3b LDS record cache (64KB); expected bucket ~12.8K

typedef float f32x4 __attribute__((ext_vector_type(4)));
typedef short short8 __attribute__((ext_vector_type(8)));
typedef unsigned int u32;

// DPP butterfly adds (VALU): 0xB1 quad_perm xor1, 0x4E quad_perm xor2,
// 0x141 row_half_mirror, 0x128 row_ror:8 (xor-8 within the 16-lane row).
#define DPPADD(v, ctrl) ((v) + __int_as_float(__builtin_amdgcn_update_dpp( \
        0, __float_as_int(v), (ctrl), 0xF, 0xF, true)))

__device__ inline short f2bf(float f) {
    union { float f; uint32_t u; } x; x.f = f;
    uint32_t r = x.u + 0x7FFF + ((x.u >> 16) & 1);   // RNE
    return (short)(r >> 16);
}
__device__ inline float bf2f(unsigned short u) {
    union { uint32_t u; float f; } x; x.u = ((uint32_t)u) << 16; return x.f;
}

// ---- K_init: ego fp32->bf16 + W^T frag pack (no more head_cnt) ------------
__global__ void __launch_bounds__(256) k_init_bf(
        const float* __restrict__ ego, unsigned short* __restrict__ ego_bf,
        int NE8, const float* __restrict__ rw, short* __restrict__ wfrag) {
    int i = blockIdx.x * 256 + threadIdx.x;
    if (blockIdx.x < 16) {                 // W^T frag pack: blocks 0..15
        int r = blockIdx.x;
        int tid = threadIdx.x;
        int lane = tid & 63;
        int c = lane & 15, q = lane >> 4;
        for (int ph = 0; ph < 2; ++ph) {
            int pair = (tid >> 6) + ph * 4;
            int t4 = pair >> 1, kh = pair & 1;
            int m = t4 * 16 + c;
            short8 f;
            for (int j = 0; j < 8; ++j) {
                int k = kh * 32 + q * 8 + j;
                f[j] = f2bf(rw[r * 4096 + k * 64 + m]);
            }
            *(short8*)(wfrag + ((size_t)((r * 4 + t4) * 2 + kh) * 64 + lane) * 8) = f;
        }
    }
    if (i >= NE8) return;
    const float4* p = (const float4*)ego + (size_t)i * 2;
    float4 a = p[0], b = p[1];
    short8 v;
    v[0] = f2bf(a.x); v[1] = f2bf(a.y); v[2] = f2bf(a.z); v[3] = f2bf(a.w);
    v[4] = f2bf(b.x); v[5] = f2bf(b.y); v[6] = f2bf(b.z); v[7] = f2bf(b.w);
    *(short8*)(ego_bf + (size_t)i * 8) = v;
}

// ---- K1: two-pass bucket-bin, LDS atomics ONLY (no global atomics) --------
// rec = tail(0..19) | type<<20 | (h & 255)<<24; bucket known from segment.
__global__ void __launch_bounds__(512) k1_bin(
        const int* __restrict__ head, const int* __restrict__ tail,
        const int* __restrict__ etype, int E, int NB,
        u32* __restrict__ staging, int* __restrict__ blk_off) {
    __shared__ int lcnt[NBMAX], lfill[NBMAX];
    int t = threadIdx.x;
    for (int b = t; b < NBMAX; b += 512) lcnt[b] = 0;
    __syncthreads();
    long long base = (long long)blockIdx.x * K1CH;
    #pragma unroll
    for (int s = 0; s < K1CH / 512; ++s) {           // pass 1: count only
        long long e = base + t + s * 512;
        if (e < E) atomicAdd(&lcnt[head[e] >> BSH], 1);
    }
    __syncthreads();
    if (t < 64) {                          // exclusive scan, 8 buckets/lane
        int cl[8]; int cs = 0;
        #pragma unroll
        for (int j = 0; j < 8; ++j) { cl[j] = lcnt[t * 8 + j]; cs += cl[j]; }
        int inc = cs;
        for (int off = 1; off < 64; off <<= 1) {
            int u = __shfl_up(inc, off);
            if (t >= off) inc += u;
        }
        int run = inc - cs;
        #pragma unroll
        for (int j = 0; j < 8; ++j) { lfill[t * 8 + j] = run; run += cl[j]; }
    }
    __syncthreads();
    int* bo = blk_off + (size_t)blockIdx.x * (NBMAX + 1);
    for (int b = t; b < NB; b += 512) bo[b] = lfill[b];
    if (t == 0) {
        long long nv = (long long)E - base;
        bo[NB] = (int)(nv < K1CH ? nv : K1CH);
    }
    __syncthreads();                                  // bo snapshot before mutate
    #pragma unroll
    for (int s = 0; s < K1CH / 512; ++s) {           // pass 2: place
        long long e = base + t + s * 512;
        if (e < E) {
            int h = head[e];
            int rk = atomicAdd(&lfill[h >> BSH], 1);
            staging[base + rk] = (u32)tail[e] | ((u32)etype[e] << 20)
                               | ((u32)(h & ((1 << BSH) - 1)) << 24);
        }
    }
}

// ---- K2s1: bucket totals (one block per bucket, sums its column) -----------
__global__ void __launch_bounds__(256) k2s1(const int* __restrict__ blk_off,
                                            int nblk, int* __restrict__ bucket_tot) {
    __shared__ int sw[4];
    int b = blockIdx.x, t = threadIdx.x;
    int s = 0;
    for (int blk = t; blk < nblk; blk += 256) {
        const int* bo = blk_off + (size_t)blk * (NBMAX + 1) + b;
        s += bo[1] - bo[0];
    }
    for (int off = 32; off; off >>= 1) s += __shfl_down(s, off);
    int w = t >> 6, lane = t & 63;
    if (lane == 0) sw[w] = s;
    __syncthreads();
    if (t == 0) bucket_tot[b] = sw[0] + sw[1] + sw[2] + sw[3];
}

// ---- K2s2: scan of NB bucket totals -> bucket_base; head_off[N]=E ----------
__global__ void __launch_bounds__(512) k2s2(const int* __restrict__ bucket_tot,
                                            int NB, int* __restrict__ bucket_base,
                                            int* __restrict__ head_off, int N, int E) {
    __shared__ int s[512];
    int t = threadIdx.x;
    int v = (t < NB) ? bucket_tot[t] : 0;
    s[t] = v;
    __syncthreads();
    for (int off = 1; off < 512; off <<= 1) {
        int x = (t >= off) ? s[t - off] : 0;
        __syncthreads();
        s[t] += x;
        __syncthreads();
    }
    if (t < NB) bucket_base[t] = s[t] - v;
    if (t == 0) head_off[N] = E;
}

// ---- K3b: per-bucket count + scan + place; writes head_off locally ---------
// Phase A: flat-walk (binary search over segment prefix) staging -> LDS cache
// + 256 per-head LDS counters. Scan -> local offsets; write head_off for this
// bucket's 256 heads. Phase B: place records head-sorted (LDS rank atomics).
__global__ void __launch_bounds__(512) k3b_rank(
        const u32* __restrict__ staging, const int* __restrict__ blk_off,
        int nblk, const int* __restrict__ bucket_base,
        int* __restrict__ head_off, int* __restrict__ recs2, int N) {
    __shared__ int soff[NBLKMAX], spre[NBLKMAX + 1];
    __shared__ int lcnt[256], lofs[256], lfill[256];
    __shared__ u32 lrec[CAP];
    int t = threadIdx.x;
    if (t < 256) lcnt[t] = 0;
    int b = blockIdx.x;
    for (int i = t; i < nblk; i += 512) {
        const int* bo = blk_off + (size_t)i * (NBMAX + 1) + b;
        int o0 = bo[0];
        soff[i] = o0;
        spre[i] = bo[1] - o0;                         // length; scanned below
    }
    __syncthreads();
    if (t < 64) {                                     // chunked exclusive scan
        int carry = 0;
        for (int c0 = 0; c0 < nblk; c0 += 64) {
            int idx = c0 + t;
            int v = (idx < nblk) ? spre[idx] : 0;
            int inc = v;
            for (int off = 1; off < 64; off <<= 1) {
                int u = __shfl_up(inc, off);
                if (t >= off) inc += u;
            }
            if (idx < nblk) spre[idx] = inc - v + carry;
            carry += __shfl(inc, 63);
        }
        if (t == 0) spre[nblk] = carry;
    }
    __syncthreads();
    int total = spre[nblk];
    int base_g = bucket_base[b];
    int hbase = b << BSH;
    auto fetch = [&](int t0) -> u32 {                 // search + read staging
        int lo = 0, hi = nblk;
        while (hi - lo > 1) {
            int mid = (lo + hi) >> 1;
            if (spre[mid] <= t0) lo = mid; else hi = mid;
        }
        return staging[(size_t)lo * K1CH + soff[lo] + (t0 - spre[lo])];
    };
    for (int t0 = t; t0 < total; t0 += 512) {         // phase A: cache + count
        u32 rec = fetch(t0);
        if (t0 < CAP) lrec[t0] = rec;
        atomicAdd(&lcnt[rec >> 24], 1);
    }
    __syncthreads();
    if (t < 64) {                                     // scan 256 counters
        int cl[4]; int cs = 0;
        #pragma unroll
        for (int j = 0; j < 4; ++j) { cl[j] = lcnt[t * 4 + j]; cs += cl[j]; }
        int inc = cs;
        for (int off = 1; off < 64; off <<= 1) {
            int u = __shfl_up(inc, off);
            if (t >= off) inc += u;
        }
        int run = inc - cs;
        #pragma unroll
        for (int j = 0; j < 4; ++j) {
            lofs[t * 4 + j] = run; lfill[t * 4 + j] = run; run += cl[j];
        }
    }
    __syncthreads();
    if (t < 256 && hbase + t < N)                     // this bucket's head_off
        head_off[hbase + t] = base_g + lofs[t];
    for (int t0 = t; t0 < total; t0 += 512) {         // phase B: place
        u32 rec = (t0 < CAP) ? lrec[t0] : fetch(t0);
        int rk = atomicAdd(&lfill[rec >> 24], 1);
        recs2[base_g + rk] = (int)(rec & 0xFFFFFF);
    }
}

// ---- K4: fused transform + score + softmax + aggregate ---------------------
// Phase 2: 2-deep pipeline (load recs b+2 / gather rows b+1 / compute b).
__global__ void __launch_bounds__(512, 4) k4_fused(
        const unsigned short* __restrict__ ego_bf,
        const short* __restrict__ wfrag,
        const int* __restrict__ recs2,
        const int* __restrict__ head_off,
        float* __restrict__ out, int N) {
    __shared__ unsigned short T[16 * HPG * TSTR];   // 73,728 B -> 2 blocks/CU
    int tid = threadIdx.x;
    int wave = tid >> 6;
    int lane = tid & 63;
    int c = lane & 15, q = lane >> 4;
    int hb = blockIdx.x * HPG;

    // ---------------- phase 1: per-wave 2 types x 32 heads ----------------
    for (int t = 0; t < 2; ++t) {
        int r = wave * 2 + t;
        const short* wp = wfrag + (size_t)r * 4096;
        short8 wf[4][2];
        #pragma unroll
        for (int t4 = 0; t4 < 4; ++t4)
            #pragma unroll
            for (int kh = 0; kh < 2; ++kh)
                wf[t4][kh] = *(const short8*)(wp + ((size_t)((t4 * 2 + kh) * 64 + lane)) * 8);
        #pragma unroll
        for (int hf = 0; hf < 2; ++hf) {
            int hrow = hb + hf * 16 + c;
            if (hrow >= N) hrow = N - 1;           // clamp; garbage T never read
            const unsigned short* hr = ego_bf + (size_t)hrow * 64;
            short8 b0 = *(const short8*)(hr + q * 8);
            short8 b1 = *(const short8*)(hr + 32 + q * 8);
            #pragma unroll
            for (int t4 = 0; t4 < 4; ++t4) {
                f32x4 a = {0.f, 0.f, 0.f, 0.f};
                a = __builtin_amdgcn_mfma_f32_16x16x32_bf16(wf[t4][0], b0, a, 0, 0, 0);
                a = __builtin_amdgcn_mfma_f32_16x16x32_bf16(wf[t4][1], b1, a, 0, 0, 0);
                ushort4 us;
                us.x = (unsigned short)f2bf(a[0]);
                us.y = (unsigned short)f2bf(a[1]);
                us.z = (unsigned short)f2bf(a[2]);
                us.w = (unsigned short)f2bf(a[3]);
                *(ushort4*)&T[(size_t)(r * HPG + hf * 16 + c) * TSTR + t4 * 16 + q * 4] = us;
            }
        }
    }
    __syncthreads();

    // ---------------- phase 2: quarter (wave,q) owns head hb + wave*4 + q --
    int hql = wave * 4 + q;
    int h = hb + hql;
    if (h >= N) return;
    int lq = c;                   // lane within quarter
    int g2 = lq >> 3, c8 = lq & 7;
    int qb = q * 16;
    int s0 = head_off[h], s1 = head_off[h + 1];
    int cnt = s1 - s0;
    int nbt = (cnt + 15) >> 4;
    float acc[8] = {0.f, 0.f, 0.f, 0.f, 0.f, 0.f, 0.f, 0.f};
    float den = 0.f;

    auto loadRec = [&](int b) -> int {             // one coalesced 4B/lane load
        if (b >= nbt) return 0;
        int idx = s0 + b * 16 + lq;
        return (idx < s1) ? recs2[idx] : 0;
    };

    int rjA[8]; short8 rowsA[8];
    int recL1;
    {
        int recL0 = loadRec(0);
        #pragma unroll
        for (int j = 0; j < 8; ++j) rjA[j] = __shfl(recL0, qb + j * 2 + g2);
        #pragma unroll
        for (int j = 0; j < 8; ++j)
            rowsA[j] = *(const short8*)(ego_bf + (size_t)(rjA[j] & 0xFFFFF) * 64 + c8 * 8);
        recL1 = loadRec(1);
    }
    for (int b = 0; b < nbt; ++b) {
        int recL2 = loadRec(b + 2);                // S(b+2)
        int rjB[8]; short8 rowsB[8];
        #pragma unroll
        for (int j = 0; j < 8; ++j) rjB[j] = __shfl(recL1, qb + j * 2 + g2);
        #pragma unroll
        for (int j = 0; j < 8; ++j)                // G(b+1): in flight across C(b)
            rowsB[j] = *(const short8*)(ego_bf + (size_t)(rjB[j] & 0xFFFFF) * 64 + c8 * 8);
        int ng = s1 - (s0 + b * 16); if (ng > 16) ng = 16;
        #pragma unroll
        for (int sIt = 0; sIt < 8; ++sIt) {        // C(b)
            if (sIt * 2 < ng) {
                short8 trw = *(const short8*)&T[(size_t)(((u32)rjA[sIt] >> 20) * HPG + hql) * TSTR + c8 * 8];
                float rf[8];
                float sa = 0.f, sb = 0.f;
                #pragma unroll
                for (int k = 0; k < 4; ++k) {
                    rf[k] = bf2f((unsigned short)rowsA[sIt][k]);
                    sa += rf[k] * bf2f((unsigned short)trw[k]);
                }
                #pragma unroll
                for (int k = 4; k < 8; ++k) {
                    rf[k] = bf2f((unsigned short)rowsA[sIt][k]);
                    sb += rf[k] * bf2f((unsigned short)trw[k]);
                }
                float s = sa + sb;
                s = DPPADD(s, 0xB1);               // xor1
                s = DPPADD(s, 0x4E);               // xor2
                s = DPPADD(s, 0x141);              // other quad
                float lr = s > 0.f ? s : NEG_SLOPE * s;
                float w = (sIt * 2 + g2 < ng) ? __expf(lr) : 0.f;
                den += w;
                #pragma unroll
                for (int k = 0; k < 8; ++k) acc[k] += w * rf[k];
            }
        }
        recL1 = recL2;
        #pragma unroll
        for (int j = 0; j < 8; ++j) { rjA[j] = rjB[j]; rowsA[j] = rowsB[j]; }
    }
    den = DPPADD(den, 0x128);                      // combine 2 edge slots
    #pragma unroll
    for (int k = 0; k < 8; ++k) acc[k] = DPPADD(acc[k], 0x128);
    if (g2 == 0) {
        float sc = (cnt > 0) ? 1.f / (den * (float)cnt) : 0.f;
        float4 v0 = {acc[0] * sc, acc[1] * sc, acc[2] * sc, acc[3] * sc};
        float4 v1 = {acc[4] * sc, acc[5] * sc, acc[6] * sc, acc[7] * sc};
        float* op = out + (size_t)h * 64 + c8 * 8;
        *(float4*)op = v0;
        *(float4*)(op + 4) = v1;
    }
}

extern "C" void kernel_launch(void* const* d_in, const int* in_sizes, int n_in,
                              void* d_out, int out_size, void* d_ws, size_t ws_size,
                              hipStream_t stream) {
    const float* ego = (const float*)d_in[0];
    const float* rw  = (const float*)d_in[1];
    const int* eidx  = (const int*)d_in[2];
    const int* etyp  = (const int*)d_in[3];
    int N = in_sizes[0] / 64;
    int E = in_sizes[3];
    const int* head = eidx;
    const int* tail = eidx + E;
    float* out = (float*)d_out;

    char* ws = (char*)d_ws;
    size_t o = 0;
    auto take = [&](size_t bytes) -> char* {
        char* p = ws + o;
        o = (o + bytes + 255) & ~(size_t)255;
        return p;
    };
    int NB = (N + (1 << BSH) - 1) >> BSH;
    if (NB > NBMAX) NB = NBMAX;            // defensive; N=100K -> 391
    int nblk = (E + K1CH - 1) / K1CH;      // 5M -> 611 (< NBLKMAX)
    unsigned short* ego_bf = (unsigned short*)take((size_t)N * 64 * 2);
    short* wfrag     = (short*)take(16 * 4096 * 2);
    int* recs2       = (int*)take((size_t)E * 4);
    u32* staging     = (u32*)take((size_t)nblk * K1CH * 4);
    int* blk_off     = (int*)take((size_t)nblk * (NBMAX + 1) * 4);
    int* head_off    = (int*)take((size_t)(N + 1) * 4);
    int* bucket_tot  = (int*)take(NBMAX * 4);
    int* bucket_base = (int*)take(NBMAX * 4);
    (void)ws_size; (void)n_in; (void)out_size;

    int NE8 = N * 8;
    k_init_bf<<<(NE8 + 255) / 256, 256, 0, stream>>>(ego, ego_bf, NE8, rw, wfrag);
    k1_bin<<<nblk, 512, 0, stream>>>(head, tail, etyp, E, NB, staging, blk_off);
    k2s1<<<NB, 256, 0, stream>>>(blk_off, nblk, bucket_tot);
    k2s2<<<1, 512, 0, stream>>>(bucket_tot, NB, bucket_base, head_off, N, E);
    k3b_rank<<<NB, 512, 0, stream>>>(staging, blk_off, nblk, bucket_base,
                                     head_off, recs2, N);
    k4_fused<<<(N + HPG - 1) / HPG, 512, 0, stream>>>(ego_bf, wfrag, recs2,
                                                      head_off, out, N);
}

// Round 8
// 186.777 us; speedup vs baseline: 1.2946x; 1.0671x over previous
//
#include <hip/hip_runtime.h>
#include <stdint.h>

#define NEG_SLOPE 0.01f
#define HPG 32        // heads per block in k4_fused
#define TSTR 72       // padded T row stride (halfwords)
#define BSH 8         // head-bucket shift: bucket = head >> 8 (256 heads)
#define NBMAX 512     // max buckets (N=100K -> 391)
#define K1CH 8192     // edges per binning block
#define CAP2 8192     // per-bucket staging capacity (avg ~3200, +80 sigma)

typedef float f32x4 __attribute__((ext_vector_type(4)));
typedef short short8 __attribute__((ext_vector_type(8)));
typedef unsigned int u32;

// DPP butterfly adds (VALU): 0xB1 quad_perm xor1, 0x4E quad_perm xor2,
// 0x141 row_half_mirror, 0x128 row_ror:8 (xor-8 within the 16-lane row).
#define DPPADD(v, ctrl) ((v) + __int_as_float(__builtin_amdgcn_update_dpp( \
        0, __float_as_int(v), (ctrl), 0xF, 0xF, true)))

__device__ inline short f2bf(float f) {
    union { float f; uint32_t u; } x; x.f = f;
    uint32_t r = x.u + 0x7FFF + ((x.u >> 16) & 1);   // RNE
    return (short)(r >> 16);
}
__device__ inline float bf2f(unsigned short u) {
    union { uint32_t u; float f; } x; x.u = ((uint32_t)u) << 16; return x.f;
}

// ---- kA: fused {bucket-major edge bin} + {ego cvt + W^T pack} --------------
// Blocks [0, nblk): two-pass bin. Count per bucket in LDS; ONE global
// atomicAdd per (block,bucket) reserves a range in staging[bucket][...];
// pass 2 places records (LDS rank atomics). rec = tail | type<<20 | hlow<<24.
// Blocks [nblk, ...): ego fp32->bf16 (coalesced) + W frag pack + head_off[N]=E.
__global__ void __launch_bounds__(512) kA(
        const int* __restrict__ head, const int* __restrict__ tail,
        const int* __restrict__ etype, int E, int NB, int nblk,
        u32* __restrict__ staging, int* bucket_cur,
        const float* __restrict__ ego, unsigned short* __restrict__ ego_bf,
        int NE8, const float* __restrict__ rw, short* __restrict__ wfrag,
        int* __restrict__ head_off, int N) {
    int t = threadIdx.x;
    int bid = blockIdx.x;
    if (bid < nblk) {
        __shared__ int lcnt[NBMAX], lbase[NBMAX], lfill[NBMAX];
        for (int b = t; b < NBMAX; b += 512) lcnt[b] = 0;
        __syncthreads();
        long long base = (long long)bid * K1CH;
        #pragma unroll
        for (int s = 0; s < K1CH / 512; ++s) {       // pass 1: count
            long long e = base + t + s * 512;
            if (e < E) atomicAdd(&lcnt[head[e] >> BSH], 1);
        }
        __syncthreads();
        for (int b = t; b < NB; b += 512) {          // one reservation/bucket
            int c = lcnt[b];
            lbase[b] = c ? atomicAdd(&bucket_cur[b], c) : 0;
            lfill[b] = 0;
        }
        __syncthreads();
        #pragma unroll
        for (int s = 0; s < K1CH / 512; ++s) {       // pass 2: place
            long long e = base + t + s * 512;
            if (e < E) {
                int h = head[e];
                int bk = h >> BSH;
                int rk = atomicAdd(&lfill[bk], 1);
                int pos = lbase[bk] + rk;
                if (pos >= CAP2) pos = CAP2 - 1;     // defensive clamp
                staging[(size_t)bk * CAP2 + pos] =
                    (u32)tail[e] | ((u32)etype[e] << 20) | ((u32)(h & 255) << 24);
            }
        }
    } else {
        int ib = bid - nblk;
        if (ib == 0 && t == 0) head_off[N] = E;
        if (ib < 16) {                               // W^T frag pack, r = ib
            int r = ib;
            int lane = t & 63;
            int c = lane & 15, q = lane >> 4;
            int pair = t >> 6;                       // 8 waves -> 8 pairs
            int t4 = pair >> 1, kh = pair & 1;
            int m = t4 * 16 + c;
            short8 f;
            for (int j = 0; j < 8; ++j) {
                int k = kh * 32 + q * 8 + j;
                f[j] = f2bf(rw[r * 4096 + k * 64 + m]);
            }
            *(short8*)(wfrag + ((size_t)((r * 4 + t4) * 2 + kh) * 64 + lane) * 8) = f;
        }
        int i = ib * 512 + t;
        if (i < NE8) {
            const float4* p = (const float4*)ego + (size_t)i * 2;
            float4 a = p[0], b = p[1];
            short8 v;
            v[0] = f2bf(a.x); v[1] = f2bf(a.y); v[2] = f2bf(a.z); v[3] = f2bf(a.w);
            v[4] = f2bf(b.x); v[5] = f2bf(b.y); v[6] = f2bf(b.z); v[7] = f2bf(b.w);
            *(short8*)(ego_bf + (size_t)i * 8) = v;
        }
    }
}

// ---- kB: per-bucket count + scan + head_off + head-sorted place ------------
// Bucket b's records are contiguous -> fully coalesced read, no search.
// bucket_base recomputed in-block from the 391 cursor totals (L2-hot).
__global__ void __launch_bounds__(512) kB(
        const u32* __restrict__ staging, const int* __restrict__ bucket_cur,
        int* __restrict__ head_off, int* __restrict__ recs2, int N, int NB) {
    __shared__ int pre[NBMAX];
    __shared__ int lcnt[256], lofs[256], lfill[256];
    __shared__ u32 lrec[CAP2];
    int t = threadIdx.x;
    int b = blockIdx.x;
    if (t < 256) lcnt[t] = 0;
    int v = (t < NB) ? bucket_cur[t] : 0;
    pre[t] = v;
    __syncthreads();
    for (int off = 1; off < 512; off <<= 1) {        // inclusive scan
        int x = (t >= off) ? pre[t - off] : 0;
        __syncthreads();
        pre[t] += x;
        __syncthreads();
    }
    int cnt_raw = bucket_cur[b];
    int base_g = pre[b] - cnt_raw;                   // exclusive prefix
    int cntb = cnt_raw > CAP2 ? CAP2 : cnt_raw;
    int hbase = b << BSH;
    const u32* sb = staging + (size_t)b * CAP2;
    for (int t0 = t; t0 < cntb; t0 += 512) {         // phase A: cache + count
        u32 rec = sb[t0];
        lrec[t0] = rec;
        atomicAdd(&lcnt[rec >> 24], 1);
    }
    __syncthreads();
    if (t < 64) {                                    // scan 256 counters
        int cl[4]; int cs = 0;
        #pragma unroll
        for (int j = 0; j < 4; ++j) { cl[j] = lcnt[t * 4 + j]; cs += cl[j]; }
        int inc = cs;
        for (int off = 1; off < 64; off <<= 1) {
            int u = __shfl_up(inc, off);
            if (t >= off) inc += u;
        }
        int run = inc - cs;
        #pragma unroll
        for (int j = 0; j < 4; ++j) {
            lofs[t * 4 + j] = run; lfill[t * 4 + j] = run; run += cl[j];
        }
    }
    __syncthreads();
    if (t < 256 && hbase + t < N)                    // this bucket's head_off
        head_off[hbase + t] = base_g + lofs[t];
    for (int t0 = t; t0 < cntb; t0 += 512) {         // phase B: place
        u32 rec = lrec[t0];
        int rk = atomicAdd(&lfill[rec >> 24], 1);
        recs2[base_g + rk] = (int)(rec & 0xFFFFFF);
    }
}

// ---- K4: fused transform + score + softmax + aggregate ---------------------
// (unchanged from the measured 76.2us version: 2-deep pipeline)
__global__ void __launch_bounds__(512, 4) k4_fused(
        const unsigned short* __restrict__ ego_bf,
        const short* __restrict__ wfrag,
        const int* __restrict__ recs2,
        const int* __restrict__ head_off,
        float* __restrict__ out, int N) {
    __shared__ unsigned short T[16 * HPG * TSTR];   // 73,728 B -> 2 blocks/CU
    int tid = threadIdx.x;
    int wave = tid >> 6;
    int lane = tid & 63;
    int c = lane & 15, q = lane >> 4;
    int hb = blockIdx.x * HPG;

    // ---------------- phase 1: per-wave 2 types x 32 heads ----------------
    for (int t = 0; t < 2; ++t) {
        int r = wave * 2 + t;
        const short* wp = wfrag + (size_t)r * 4096;
        short8 wf[4][2];
        #pragma unroll
        for (int t4 = 0; t4 < 4; ++t4)
            #pragma unroll
            for (int kh = 0; kh < 2; ++kh)
                wf[t4][kh] = *(const short8*)(wp + ((size_t)((t4 * 2 + kh) * 64 + lane)) * 8);
        #pragma unroll
        for (int hf = 0; hf < 2; ++hf) {
            int hrow = hb + hf * 16 + c;
            if (hrow >= N) hrow = N - 1;           // clamp; garbage T never read
            const unsigned short* hr = ego_bf + (size_t)hrow * 64;
            short8 b0 = *(const short8*)(hr + q * 8);
            short8 b1 = *(const short8*)(hr + 32 + q * 8);
            #pragma unroll
            for (int t4 = 0; t4 < 4; ++t4) {
                f32x4 a = {0.f, 0.f, 0.f, 0.f};
                a = __builtin_amdgcn_mfma_f32_16x16x32_bf16(wf[t4][0], b0, a, 0, 0, 0);
                a = __builtin_amdgcn_mfma_f32_16x16x32_bf16(wf[t4][1], b1, a, 0, 0, 0);
                ushort4 us;
                us.x = (unsigned short)f2bf(a[0]);
                us.y = (unsigned short)f2bf(a[1]);
                us.z = (unsigned short)f2bf(a[2]);
                us.w = (unsigned short)f2bf(a[3]);
                *(ushort4*)&T[(size_t)(r * HPG + hf * 16 + c) * TSTR + t4 * 16 + q * 4] = us;
            }
        }
    }
    __syncthreads();

    // ---------------- phase 2: quarter (wave,q) owns head hb + wave*4 + q --
    int hql = wave * 4 + q;
    int h = hb + hql;
    if (h >= N) return;
    int lq = c;                   // lane within quarter
    int g2 = lq >> 3, c8 = lq & 7;
    int qb = q * 16;
    int s0 = head_off[h], s1 = head_off[h + 1];
    int cnt = s1 - s0;
    int nbt = (cnt + 15) >> 4;
    float acc[8] = {0.f, 0.f, 0.f, 0.f, 0.f, 0.f, 0.f, 0.f};
    float den = 0.f;

    auto loadRec = [&](int b) -> int {             // one coalesced 4B/lane load
        if (b >= nbt) return 0;
        int idx = s0 + b * 16 + lq;
        return (idx < s1) ? recs2[idx] : 0;
    };

    int rjA[8]; short8 rowsA[8];
    int recL1;
    {
        int recL0 = loadRec(0);
        #pragma unroll
        for (int j = 0; j < 8; ++j) rjA[j] = __shfl(recL0, qb + j * 2 + g2);
        #pragma unroll
        for (int j = 0; j < 8; ++j)
            rowsA[j] = *(const short8*)(ego_bf + (size_t)(rjA[j] & 0xFFFFF) * 64 + c8 * 8);
        recL1 = loadRec(1);
    }
    for (int b = 0; b < nbt; ++b) {
        int recL2 = loadRec(b + 2);                // S(b+2)
        int rjB[8]; short8 rowsB[8];
        #pragma unroll
        for (int j = 0; j < 8; ++j) rjB[j] = __shfl(recL1, qb + j * 2 + g2);
        #pragma unroll
        for (int j = 0; j < 8; ++j)                // G(b+1): in flight across C(b)
            rowsB[j] = *(const short8*)(ego_bf + (size_t)(rjB[j] & 0xFFFFF) * 64 + c8 * 8);
        int ng = s1 - (s0 + b * 16); if (ng > 16) ng = 16;
        #pragma unroll
        for (int sIt = 0; sIt < 8; ++sIt) {        // C(b)
            if (sIt * 2 < ng) {
                short8 trw = *(const short8*)&T[(size_t)(((u32)rjA[sIt] >> 20) * HPG + hql) * TSTR + c8 * 8];
                float rf[8];
                float sa = 0.f, sb = 0.f;
                #pragma unroll
                for (int k = 0; k < 4; ++k) {
                    rf[k] = bf2f((unsigned short)rowsA[sIt][k]);
                    sa += rf[k] * bf2f((unsigned short)trw[k]);
                }
                #pragma unroll
                for (int k = 4; k < 8; ++k) {
                    rf[k] = bf2f((unsigned short)rowsA[sIt][k]);
                    sb += rf[k] * bf2f((unsigned short)trw[k]);
                }
                float s = sa + sb;
                s = DPPADD(s, 0xB1);               // xor1
                s = DPPADD(s, 0x4E);               // xor2
                s = DPPADD(s, 0x141);              // other quad
                float lr = s > 0.f ? s : NEG_SLOPE * s;
                float w = (sIt * 2 + g2 < ng) ? __expf(lr) : 0.f;
                den += w;
                #pragma unroll
                for (int k = 0; k < 8; ++k) acc[k] += w * rf[k];
            }
        }
        recL1 = recL2;
        #pragma unroll
        for (int j = 0; j < 8; ++j) { rjA[j] = rjB[j]; rowsA[j] = rowsB[j]; }
    }
    den = DPPADD(den, 0x128);                      // combine 2 edge slots
    #pragma unroll
    for (int k = 0; k < 8; ++k) acc[k] = DPPADD(acc[k], 0x128);
    if (g2 == 0) {
        float sc = (cnt > 0) ? 1.f / (den * (float)cnt) : 0.f;
        float4 v0 = {acc[0] * sc, acc[1] * sc, acc[2] * sc, acc[3] * sc};
        float4 v1 = {acc[4] * sc, acc[5] * sc, acc[6] * sc, acc[7] * sc};
        float* op = out + (size_t)h * 64 + c8 * 8;
        *(float4*)op = v0;
        *(float4*)(op + 4) = v1;
    }
}

extern "C" void kernel_launch(void* const* d_in, const int* in_sizes, int n_in,
                              void* d_out, int out_size, void* d_ws, size_t ws_size,
                              hipStream_t stream) {
    const float* ego = (const float*)d_in[0];
    const float* rw  = (const float*)d_in[1];
    const int* eidx  = (const int*)d_in[2];
    const int* etyp  = (const int*)d_in[3];
    int N = in_sizes[0] / 64;
    int E = in_sizes[3];
    const int* head = eidx;
    const int* tail = eidx + E;
    float* out = (float*)d_out;

    char* ws = (char*)d_ws;
    size_t o = 0;
    auto take = [&](size_t bytes) -> char* {
        char* p = ws + o;
        o = (o + bytes + 255) & ~(size_t)255;
        return p;
    };
    int NB = (N + (1 << BSH) - 1) >> BSH;
    if (NB > NBMAX) NB = NBMAX;            // defensive; N=100K -> 391
    int nblk = (E + K1CH - 1) / K1CH;      // 1.25M -> 153
    int NE8 = N * 8;
    int nbI = (NE8 + 511) / 512;           // init blocks (>= 16 for W pack)
    if (nbI < 16) nbI = 16;
    unsigned short* ego_bf = (unsigned short*)take((size_t)N * 64 * 2);
    short* wfrag    = (short*)take(16 * 4096 * 2);
    int* recs2      = (int*)take((size_t)E * 4);
    u32* staging    = (u32*)take((size_t)NB * CAP2 * 4);
    int* bucket_cur = (int*)take(NBMAX * 4);
    int* head_off   = (int*)take((size_t)(N + 1) * 4);
    (void)ws_size; (void)n_in; (void)out_size;

    hipMemsetAsync(bucket_cur, 0, NBMAX * 4, stream);
    kA<<<nblk + nbI, 512, 0, stream>>>(head, tail, etyp, E, NB, nblk,
                                       staging, bucket_cur,
                                       ego, ego_bf, NE8, rw, wfrag,
                                       head_off, N);
    kB<<<NB, 512, 0, stream>>>(staging, bucket_cur, head_off, recs2, N, NB);
    k4_fused<<<(N + HPG - 1) / HPG, 512, 0, stream>>>(ego_bf, wfrag, recs2,
                                                      head_off, out, N);
}